// Round 2
// baseline (196.211 us; speedup 1.0000x reference)
//
#include <hip/hip_runtime.h>

// Boundary_binaryLoss: 15x15 binary morphology boundary mask + masked NLL mean.
// B=32, C=2, H=480, W=864. logits [B,C,H,W] f32, labels [B,H,W] i32 in {0,1,255}.
//
// valid(b,h,w) = (label != 255) && (clipped 15x15 window contains a pixel with
//   np_label==0 (label 0 or 255) AND a pixel with np_label==255 (label 1))
// loss = -sum(valid ? logits[b,label,h,w] : 0) / max(#valid, 1)
//
// R1: same-line device atomics serialized (180us) -> per-block double2 partials.
// R2: register-prefetch of logits was silently sunk by the compiler (VGPR=24
//     proved it) -> latency re-exposed at block tail.
// R3: global_load_lds DMA for logits. NEUTRAL: __syncthreads() drains
//     vmcnt(0) (compiler emits s_waitcnt vmcnt(0) before s_barrier), so the
//     DMA was drained at the FIRST barrier with only ~60 ops of cover. And
//     23.5 KB LDS dropped occupancy 63->44%. Lesson: with __syncthreads in
//     the chain, no prefetch survives.
// R4: remove the barriers. One autonomous WAVE per 50x32 output tile, no LDS,
//     no __syncthreads:
//       - lane = column; 46 label rows packed 2 bits/row into 3 VGPRs
//       - horizontal 15-OR: log-doubling window OR via 4 shfl_down + 1
//         shfl_up (garbage confined to lanes >=50, never consumed)
//       - vertical 15-OR: 4 shift-OR steps on u64 row-packs
//       - logits: picked-channel load only, predicated to the 50 output lanes
//     Loads are never drained by a barrier; scoreboarding + ~8 waves/SIMD of
//     independent work hide all latency. Floors: ~6 us VALU, ~25 us HBM.

namespace {
constexpr int B_ = 32;
constexpr int H_ = 480;
constexpr int W_ = 864;
constexpr int HW = H_ * W_;
constexpr int R_ = 7;
constexpr int OC = 50;                    // output cols per wave (64 - 2*R_)
constexpr int TH_ = 32;                   // output rows per wave
constexpr int LH = TH_ + 2 * R_;          // 46 label rows read
constexpr int NSX = (W_ + OC - 1) / OC;   // 18 col-strips (last is 14 wide)
constexpr int NSY = H_ / TH_;             // 15 row-chunks
constexpr int NTILE = B_ * NSY * NSX;     // 8640 wave-tiles
constexpr int WPB = 4;                    // waves per block
constexpr int NBLKP = NTILE / WPB;        // 2160 blocks
} // namespace

// 15-wide centered window-OR across lanes, applied to a 2-bit x 16-row pack.
// G[l] = OR_{d=0..14} x[l+d] via log-doubling; H[l] = G[l-7].
// Shuffle out-of-range garbage propagates only to G[l>=50]; H is consumed
// only at lanes 7..56 -> G[0..49] -> garbage-free.
__device__ __forceinline__ unsigned hwin15(unsigned x) {
  unsigned a = x | __shfl_down(x, 1, 64);   // d: 0..1
  a |= __shfl_down(a, 2, 64);               // 0..3
  a |= __shfl_down(a, 4, 64);               // 0..7
  a |= __shfl_down(a, 7, 64);               // 0..14
  return __shfl_up(a, 7, 64);               // center: -7..+7
}

extern "C" __global__ __launch_bounds__(256, 6)
void boundary_loss_main(const float* __restrict__ logits,
                        const int* __restrict__ labels,
                        double2* __restrict__ partials)
{
  __shared__ double red_s[WPB];
  __shared__ unsigned red_c[WPB];

  const int tid = threadIdx.x;
  const int lane = tid & 63;
  const int wv = tid >> 6;
  const int t = blockIdx.x * WPB + wv;      // wave-tile id, 0..8639
  const int b  = t / (NSY * NSX);
  const int rr = t - b * (NSY * NSX);
  const int sy = rr / NSX;
  const int sx = rr - sy * NSX;

  const int gr0 = sy * TH_;                 // first output image row
  const int col = sx * OC - R_ + lane;      // this lane's image column
  const bool colok = (col >= 0) && (col < W_);
  const int colc = col < 0 ? 0 : (col >= W_ ? W_ - 1 : col);

  const int* __restrict__ lab = labels + b * HW;
  const float* __restrict__ lg = logits + (size_t)(2 * b) * HW;

  // ---- phase 1: 46 coalesced label rows -> packed flags (2 bits/row) ----
  // f bit0: label in {0,255} (np_label==0); f bit1: label==1 (np_label==255)
  // c bit0: label==1 (channel select); c bit1: label==255 (ignore)
  unsigned f0 = 0, f1 = 0, f2 = 0, c0 = 0, c1 = 0, c2 = 0;
#pragma unroll
  for (int a = 0; a < LH; ++a) {
    const int gr = gr0 - R_ + a;
    const int grc = gr < 0 ? 0 : (gr >= H_ ? H_ - 1 : gr);
    const int v = lab[grc * W_ + colc];
    unsigned f = (unsigned)((v == 0) | (v == 255)) | ((unsigned)(v == 1) << 1);
    const unsigned c = (unsigned)(v == 1) | ((unsigned)(v == 255) << 1);
    if (gr < 0 || gr >= H_) f = 0;          // clipped window: no contribution
    const int sh = 2 * (a & 15);
    if (a < 16)      { f0 |= f << sh; c0 |= c << sh; }
    else if (a < 32) { f1 |= f << sh; c1 |= c << sh; }
    else             { f2 |= f << sh; c2 |= c << sh; }
  }
  if (!colok) { f0 = f1 = f2 = 0; }         // clipped window at image L/R edge

  // ---- phase 2: horizontal 15-OR (all 46 rows via 3 packed shuffles) ----
  const unsigned h0 = hwin15(f0);
  const unsigned h1 = hwin15(f1);
  const unsigned h2 = hwin15(f2);

  // ---- phase 3: vertical 15-OR via u64 shift-OR doubling (even shifts
  //      keep the two flag bit-lanes separate) ----
  unsigned long long A  = (unsigned long long)h0 | ((unsigned long long)h1 << 32);
  unsigned long long Bv = (unsigned long long)h1 | ((unsigned long long)h2 << 32);
  A  |= A  >> 2;  A  |= A  >> 4;  A  |= A  >> 8;  A  |= A  >> 14;  // rows r..r+14
  Bv |= Bv >> 2;  Bv |= Bv >> 4;  Bv |= Bv >> 8;  Bv |= Bv >> 14;

  // ---- phase 4: picked-channel logits gather + masked accumulate ----
  double lsum = 0.0;
  unsigned lcnt = 0;
  const bool outlane = (lane >= R_) && (lane < R_ + OC) && colok;
  if (outlane) {                            // masked lanes issue no loads
    int lgoff = gr0 * W_ + colc;
#pragma unroll
    for (int o = 0; o < TH_; ++o, lgoff += W_) {
      const unsigned fb = (o < 18) ? ((unsigned)(A >> (2 * o)) & 3u)
                                   : ((unsigned)(Bv >> (2 * (o - 16))) & 3u);
      const int ar = o + R_;                // absolute packed-row of center
      const unsigned creg = (ar < 16) ? c0 : (ar < 32 ? c1 : c2);
      const unsigned cb = (creg >> (2 * (ar & 15))) & 3u;
      const bool ok = (fb == 3u) && ((cb & 2u) == 0u);
      const float val = lg[lgoff + (int)(cb & 1u) * HW];
      lsum += ok ? (double)val : 0.0;
      lcnt += ok ? 1u : 0u;
    }
  }

  // ---- wave + block reduction -> one double2 per block (deterministic) ----
#pragma unroll
  for (int off = 32; off > 0; off >>= 1) {
    lsum += __shfl_down(lsum, off, 64);
    lcnt += __shfl_down(lcnt, off, 64);
  }
  if ((tid & 63) == 0) { red_s[wv] = lsum; red_c[wv] = lcnt; }
  __syncthreads();                          // tail-only; nothing left to drain
  if (tid == 0) {
    const double s = red_s[0] + red_s[1] + red_s[2] + red_s[3];
    const double c = (double)(red_c[0] + red_c[1] + red_c[2] + red_c[3]);
    partials[blockIdx.x] = make_double2(s, c);
  }
}

extern "C" __global__ __launch_bounds__(1024)
void boundary_loss_final(const double2* __restrict__ partials,
                         float* __restrict__ out)
{
  __shared__ double red_s[16];
  __shared__ double red_c[16];
  const int tid = threadIdx.x;
  double s = 0.0, c = 0.0;
  for (int i = tid; i < NBLKP; i += 1024) {
    const double2 p = partials[i];
    s += p.x;
    c += p.y;
  }
#pragma unroll
  for (int off = 32; off > 0; off >>= 1) {
    s += __shfl_down(s, off, 64);
    c += __shfl_down(c, off, 64);
  }
  const int wave = tid >> 6;
  if ((tid & 63) == 0) { red_s[wave] = s; red_c[wave] = c; }
  __syncthreads();
  if (tid == 0) {
    double ts = 0.0, tc = 0.0;
#pragma unroll
    for (int i = 0; i < 16; ++i) { ts += red_s[i]; tc += red_c[i]; }
    if (tc < 1.0) tc = 1.0;
    out[0] = (float)(-ts / tc);
  }
}

extern "C" void kernel_launch(void* const* d_in, const int* in_sizes, int n_in,
                              void* d_out, int out_size, void* d_ws, size_t ws_size,
                              hipStream_t stream)
{
  const float* logits = (const float*)d_in[0];
  const int* labels = (const int*)d_in[1];
  float* out = (float*)d_out;
  double2* partials = (double2*)d_ws;  // NBLKP*16 B = 34,560 B; every slot
                                       // written by main -> no init needed.

  boundary_loss_main<<<dim3(NBLKP), 256, 0, stream>>>(logits, labels, partials);
  boundary_loss_final<<<1, 1024, 0, stream>>>(partials, out);
}